// Round 12
// baseline (6991.023 us; speedup 1.0000x reference)
//
#include <hip/hip_runtime.h>

typedef unsigned short u16;

#define NSYM 512

// ---------------------------------------------------------------------------
// Build u16 copies of the luts + fused relu(add_lut) table
// ---------------------------------------------------------------------------
__global__ void build_tables_kernel(const int* __restrict__ conv_i,
                                    const int* __restrict__ add_i,
                                    const int* __restrict__ relu_i,
                                    u16* __restrict__ conv_u,
                                    u16* __restrict__ add_u,
                                    u16* __restrict__ addrelu_u) {
    int i = blockIdx.x * blockDim.x + threadIdx.x;
    if (i < NSYM * NSYM) {
        conv_u[i] = (u16)conv_i[i];
        int a = add_i[i];
        add_u[i] = (u16)a;
        addrelu_u[i] = (u16)relu_i[a];
    }
}

// ---------------------------------------------------------------------------
// Quantize: argmin over sorted centroids == binary search + neighbor compare.
// Output layout: (img, y, x, ch), ch fastest.
// ---------------------------------------------------------------------------
__global__ void quantize_kernel(const float* __restrict__ x,
                                u16* __restrict__ s0,
                                const float* __restrict__ cent,
                                int n) {
    __shared__ float c[NSYM];
    for (int t = threadIdx.x; t < NSYM; t += blockDim.x) c[t] = cent[t];
    __syncthreads();
    int i = blockIdx.x * blockDim.x + threadIdx.x;
    if (i >= n) return;
    int ch = i % 3; int t2 = i / 3; int xx = t2 % 67; int t3 = t2 / 67;
    int y = t3 % 67; int img = t3 / 67;
    float v = x[((img * 3 + ch) * 67 + y) * 67 + xx];
    int lo = 0, hi = NSYM;
    while (lo < hi) { int mid = (lo + hi) >> 1; if (c[mid] < v) lo = mid + 1; else hi = mid; }
    int idx;
    if (lo == 0) idx = 0;
    else if (lo == NSYM) idx = NSYM - 1;
    else {
        float d1 = v - c[lo - 1];
        float d2 = v - c[lo];
        idx = (d1 * d1 <= d2 * d2) ? (lo - 1) : lo;
    }
    s0[i] = (u16)idx;
}

// ---------------------------------------------------------------------------
// Mid-layer symbolic conv (L0..L9) — unchanged round-2 structure (baseline):
// 64-thread blocks, one pixel x 64 oc, depth-3 rotating prefetch.
// ---------------------------------------------------------------------------
__global__ __launch_bounds__(64) void symconv_glob_kernel(
        const u16* __restrict__ in, u16* __restrict__ out,
        const int* __restrict__ Wl,
        const u16* __restrict__ conv,
        const u16* __restrict__ addt,
        const u16* __restrict__ addlast,
        int H, int C, int OC, int nOCG,
        int K, int ST, int PAD, int OH, int OW) {
    extern __shared__ u16 patch[];
    int bid = blockIdx.x;
    int ocg = bid % nOCG;
    int pix = bid / nOCG;
    int img = pix / (OH * OW);
    int rem = pix - img * (OH * OW);
    int oy = rem / OW;
    int ox = rem - oy * OW;
    int J = K * K * C;
    for (int t = threadIdx.x; t < J; t += 64) {
        int c = t % C; int tt = t / C; int kc = tt % K; int kr = tt / K;
        int iy = oy * ST + kr - PAD;
        int ix = ox * ST + kc - PAD;
        u16 v = 0;  // jnp.pad pads with symbol 0
        if (iy >= 0 && iy < H && ix >= 0 && ix < H)
            v = in[((img * H + iy) * H + ix) * C + c];
        patch[t] = v;
    }
    __syncthreads();
    int oc = (ocg << 6) + threadIdx.x;

#define GM(j) ((int)conv[((int)patch[(j)] << 9) + Wl[(j) * OC + oc]])

    int carry = GM(0);
    int mA = GM(1);
    int mB = GM(2);
    int mC = GM(3);
    for (int j = 1; j < J - 3; ++j) {
        int mcur = mA; mA = mB; mB = mC;
        mC = GM(j + 3);
        carry = (int)addt[(carry << 9) + mcur];
    }
    carry = (int)addt[(carry << 9) + mA];
    carry = (int)addt[(carry << 9) + mB];
    carry = (int)addlast[(carry << 9) + mC];
    out[pix * OC + oc] = (u16)carry;
#undef GM
}

// ---------------------------------------------------------------------------
// Deep-layer symbolic conv (L10..L16) — lean producer/consumer.
//   128 threads = 2 waves, one pixel x 64 oc. DCH template: 128 for L10-12
//   (70KB LDS -> 2 blocks/CU, grid=512 co-resident), 256 for L13-16
//   (140KB LDS, grid=256 -> 1 block/CU exact).
//   wave1 (producer): m2[j] = conv[patch_j, W[j,oc]] << 1, chunk t+1 into
//     double-buffered LDS. Throughput-bound, large slack vs consumer.
//   wave0 (consumer): per step the ONLY critical-path ops are
//     off = (carry<<10)+m2  (one v_lshl_add) ; carry = load_u16(addt+off).
//     m2 batch-read 8/group from LDS; LDS latency hides under gather waits.
// ---------------------------------------------------------------------------
template <int DCH>
__global__ __launch_bounds__(128) void symconv_deep_kernel(
        const u16* __restrict__ in, u16* __restrict__ out,
        const int* __restrict__ Wl,
        const u16* __restrict__ conv,
        const u16* __restrict__ addt,
        const u16* __restrict__ addlast,
        int H, int C, int OC, int nOCG,
        int K, int ST, int PAD, int OH, int OW) {
    extern __shared__ u16 lds[];
    int J = K * K * C;
    u16* patch = lds;                      // J u16 (J multiple of 8)
    u16* mbuf = lds + J;                   // 2 x 64 x DCH u16

    int bid = blockIdx.x;
    int ocg = bid % nOCG;
    int pix = bid / nOCG;
    int img = pix / (OH * OW);
    int rem = pix - img * (OH * OW);
    int oy = rem / OW;
    int ox = rem - oy * OW;
    int tid = threadIdx.x;

    // stage patch; j order = (kr, kc, c), c fastest
    for (int t = tid; t < J; t += 128) {
        int c = t % C; int tt = t / C; int kc = tt % K; int kr = tt / K;
        int iy = oy * ST + kr - PAD;
        int ix = ox * ST + kc - PAD;
        u16 v = 0;
        if (iy >= 0 && iy < H && ix >= 0 && ix < H)
            v = in[((img * H + iy) * H + ix) * C + c];
        patch[t] = v;
    }
    __syncthreads();

    int wave = tid >> 6;
    int lane = tid & 63;
    int oc = (ocg << 6) + lane;
    int nch = J / DCH;                     // exact for deep layers

    if (wave == 1) {
        // ---- producer ----
        for (int t = 0; t < nch; ++t) {
            u16* dst = mbuf + (t & 1) * (64 * DCH) + lane * DCH;
            int j0 = t * DCH;
            for (int k = 0; k < DCH; k += 8) {
                int wv[8];
                #pragma unroll
                for (int u = 0; u < 8; ++u)
                    wv[u] = Wl[(j0 + k + u) * OC + oc];
                #pragma unroll
                for (int u = 0; u < 8; ++u)
                    dst[k + u] = (u16)(conv[((int)patch[j0 + k + u] << 9) + wv[u]] << 1);
            }
            __syncthreads();               // chunk t ready
        }
    } else {
        // ---- consumer ----
        unsigned carry = 0;
        const char* ab = (const char*)addt;
        for (int t = 0; t < nch; ++t) {
            __syncthreads();               // wait for chunk t
            const u16* src = mbuf + (t & 1) * (64 * DCH) + lane * DCH;
            bool lastchunk = (t == nch - 1);
            int n2 = DCH - (lastchunk ? 1 : 0);
            unsigned m2[8], m2n[8];
            #pragma unroll
            for (int u = 0; u < 8; ++u) m2[u] = src[u];
            if (t == 0) {
                carry = m2[0] >> 1;
                #pragma unroll
                for (int u = 1; u < 8; ++u) {
                    unsigned off = (carry << 10) + m2[u];
                    carry = *(const u16*)(ab + off);
                }
            } else {
                #pragma unroll
                for (int u = 0; u < 8; ++u) {
                    unsigned off = (carry << 10) + m2[u];
                    carry = *(const u16*)(ab + off);
                }
            }
            for (int k = 8; k + 8 <= n2; k += 8) {
                #pragma unroll
                for (int u = 0; u < 8; ++u) m2n[u] = src[k + u];
                #pragma unroll
                for (int u = 0; u < 8; ++u) {
                    unsigned off = (carry << 10) + m2n[u];
                    carry = *(const u16*)(ab + off);
                }
            }
            // tail of last chunk: 7 normal steps + final addlast step
            if (lastchunk) {
                int k = (n2 / 8) * 8;      // = DCH-8
                #pragma unroll
                for (int u = 0; u < 8; ++u) m2n[u] = src[k + u];
                #pragma unroll
                for (int u = 0; u < 7; ++u) {
                    unsigned off = (carry << 10) + m2n[u];
                    carry = *(const u16*)(ab + off);
                }
                carry = addlast[(carry << 9) + (m2n[7] >> 1)];
            }
        }
        out[pix * OC + oc] = (u16)carry;
    }
    // Producer and consumer each execute exactly nch barriers (wave-uniform).
}

// ---------------------------------------------------------------------------
// Head: vals = centroid[s]; feats = mean over 2x2; out = feats @ fc_w.T + fc_b
// ---------------------------------------------------------------------------
__global__ void head_kernel(const u16* __restrict__ s,
                            const float* __restrict__ cent,
                            const float* __restrict__ fcw,
                            const float* __restrict__ fcb,
                            float* __restrict__ out) {
    __shared__ float feats[NSYM];
    int img = blockIdx.x;
    const u16* sp = s + img * 4 * NSYM;
    for (int c = threadIdx.x; c < NSYM; c += blockDim.x) {
        float acc = cent[sp[c]] + cent[sp[NSYM + c]] +
                    cent[sp[2 * NSYM + c]] + cent[sp[3 * NSYM + c]];
        feats[c] = acc * 0.25f;
    }
    __syncthreads();
    int o = blockIdx.y * blockDim.x + threadIdx.x;
    if (o < 1000) {
        float acc = fcb[o];
        const float* wr = fcw + o * NSYM;
        for (int c2 = 0; c2 < NSYM; ++c2) acc += feats[c2] * wr[c2];
        out[img * 1000 + o] = acc;
    }
}

// ---------------------------------------------------------------------------
extern "C" void kernel_launch(void* const* d_in, const int* in_sizes, int n_in,
                              void* d_out, int out_size, void* d_ws, size_t ws_size,
                              hipStream_t stream) {
    const float* x = (const float*)d_in[0];
    const int* w[17];
    for (int i = 0; i < 17; ++i) w[i] = (const int*)d_in[1 + i];
    const int* conv_i = (const int*)d_in[18];
    const int* add_i  = (const int*)d_in[19];
    const int* relu_i = (const int*)d_in[20];
    const float* cent = (const float*)d_in[21];
    const float* fcw  = (const float*)d_in[22];
    const float* fcb  = (const float*)d_in[23];
    float* out = (float*)d_out;

    char* p = (char*)d_ws;
    u16* conv_u    = (u16*)p; p += NSYM * NSYM * 2;
    u16* add_u     = (u16*)p; p += NSYM * NSYM * 2;
    u16* addrelu_u = (u16*)p; p += NSYM * NSYM * 2;
    u16* act0      = (u16*)p; p += ((8 * 67 * 67 * 3 * 2 + 255) / 256) * 256;
    u16* actA      = (u16*)p; p += 8 * 16 * 16 * 64 * 2;
    u16* actB      = (u16*)p; p += 8 * 16 * 16 * 64 * 2;

    build_tables_kernel<<<(NSYM * NSYM + 255) / 256, 256, 0, stream>>>(
        conv_i, add_i, relu_i, conv_u, add_u, addrelu_u);

    int nq = 8 * 67 * 67 * 3;
    quantize_kernel<<<(nq + 255) / 256, 256, 0, stream>>>(x, act0, cent, nq);

    struct LC { int K, ST, PAD, C, OC, H, OH, relu, deep; };
    // deep: 0 = mid kernel, 1 = deep DCH=128 (L10-12), 2 = deep DCH=256 (L13-16)
    static const LC L[17] = {
        {7,4,0,  3, 64,67,16,1, 0},
        {3,1,1, 64, 64,16,16,1, 0},
        {3,1,1, 64, 64,16,16,0, 0},
        {3,1,1, 64, 64,16,16,1, 0},
        {3,1,1, 64, 64,16,16,0, 0},
        {3,2,1, 64,128,16, 8,1, 0},
        {3,1,1,128,128, 8, 8,0, 0},
        {3,1,1,128,128, 8, 8,1, 0},
        {3,1,1,128,128, 8, 8,0, 0},
        {3,2,1,128,256, 8, 4,1, 0},
        {3,1,1,256,256, 4, 4,0, 1},
        {3,1,1,256,256, 4, 4,1, 1},
        {3,1,1,256,256, 4, 4,0, 1},
        {3,2,1,256,512, 4, 2,1, 2},
        {3,1,1,512,512, 2, 2,0, 2},
        {3,1,1,512,512, 2, 2,1, 2},
        {3,1,1,512,512, 2, 2,0, 2},
    };

    // deep-kernel dynamic LDS: patch(J*2) + 2*64*DCH*2 bytes.
    int maxlds1 = 0, maxlds2 = 0;
    for (int i = 0; i < 17; ++i) {
        int J = L[i].K * L[i].K * L[i].C;
        if (L[i].deep == 1) {
            int b = J * 2 + 2 * 64 * 128 * 2;
            if (b > maxlds1) maxlds1 = b;
        } else if (L[i].deep == 2) {
            int b = J * 2 + 2 * 64 * 256 * 2;
            if (b > maxlds2) maxlds2 = b;
        }
    }
    hipFuncSetAttribute((const void*)symconv_deep_kernel<128>,
                        hipFuncAttributeMaxDynamicSharedMemorySize, maxlds1);
    hipFuncSetAttribute((const void*)symconv_deep_kernel<256>,
                        hipFuncAttributeMaxDynamicSharedMemorySize, maxlds2);

    const u16* cur = act0;
    u16* nxt = actA;
    for (int i = 0; i < 17; ++i) {
        int OH = L[i].OH;
        int nOCG = L[i].OC / 64;
        int J = L[i].K * L[i].K * L[i].C;
        const u16* lastt = L[i].relu ? addrelu_u : add_u;
        int grid = 8 * OH * OH * nOCG;
        if (L[i].deep == 1) {
            int ldsB = J * 2 + 2 * 64 * 128 * 2;
            symconv_deep_kernel<128><<<grid, 128, ldsB, stream>>>(
                cur, nxt, w[i], conv_u, add_u, lastt,
                L[i].H, L[i].C, L[i].OC, nOCG,
                L[i].K, L[i].ST, L[i].PAD, OH, OH);
        } else if (L[i].deep == 2) {
            int ldsB = J * 2 + 2 * 64 * 256 * 2;
            symconv_deep_kernel<256><<<grid, 128, ldsB, stream>>>(
                cur, nxt, w[i], conv_u, add_u, lastt,
                L[i].H, L[i].C, L[i].OC, nOCG,
                L[i].K, L[i].ST, L[i].PAD, OH, OH);
        } else {
            symconv_glob_kernel<<<grid, 64, J * 2, stream>>>(
                cur, nxt, w[i], conv_u, add_u, lastt,
                L[i].H, L[i].C, L[i].OC, nOCG,
                L[i].K, L[i].ST, L[i].PAD, OH, OH);
        }
        cur = nxt;
        nxt = (nxt == actA) ? actB : actA;
    }

    head_kernel<<<dim3(8, 4), 256, 0, stream>>>(cur, cent, fcw, fcb, out);
}